// Round 3
// baseline (487.361 us; speedup 1.0000x reference)
//
#include <hip/hip_runtime.h>
#include <cmath>
#include <complex>

#define T_TAB 4096
#define G_TAB 8
#define NN 16384
#define CH 16

// ---------------- CG tables (exact host-side port of the reference) ----------------
struct CGPack {
  float c000[1];
  float c110[9];
  float c220[25];
  float c330[49];
  float c011[9];
  float c101[9];
  float c111[27];
  float c121[45];
  float c211[45];
  float c221[75];
  float c231[105];
  float c321[105];
  float c331[147];
};

static double factd(int n){ double r=1.0; for(int i=2;i<=n;++i) r*=(double)i; return r; }

static double cg_coef(int j1,int m1,int j2,int m2,int j3,int m3){
  double pref = sqrt((2.0*j3+1.0)*factd(j3+j1-j2)*factd(j3-j1+j2)*factd(j1+j2-j3)/factd(j1+j2+j3+1));
  pref *= sqrt(factd(j3+m3)*factd(j3-m3)*factd(j1-m1)*factd(j1+m1)*factd(j2-m2)*factd(j2+m2));
  double s=0.0;
  for(int k=0;k<=j1+j2-j3;++k){
    int a0=k,a1=j1+j2-j3-k,a2=j1-m1-k,a3=j2+m2-k,a4=j3-j2+m1+k,a5=j3-j1-m2+k;
    if(a0<0||a1<0||a2<0||a3<0||a4<0||a5<0) continue;
    double d=factd(a0)*factd(a1)*factd(a2)*factd(a3)*factd(a4)*factd(a5);
    s += ((k&1)?-1.0:1.0)/d;
  }
  return pref*s;
}

static void u_fill(int l, std::complex<double> U[7][7]){
  for(int i=0;i<7;++i) for(int j=0;j<7;++j) U[i][j]=std::complex<double>(0.0,0.0);
  const double is2 = 1.0/sqrt(2.0);
  U[l][l]=1.0;
  for(int m=1;m<=l;++m){
    double sgn = (m&1)?-1.0:1.0;
    U[l+m][l+m] = sgn*is2;
    U[l+m][l-m] = is2;
    U[l-m][l-m] = std::complex<double>(0.0, is2);
    U[l-m][l+m] = std::complex<double>(0.0, -sgn*is2);
  }
}

static void cg_fill(int l1,int l2,int l3, float* out){
  int n1=2*l1+1,n2=2*l2+1,n3=2*l3+1;
  double Cc[7][7][7];
  for(int a=0;a<7;++a)for(int b=0;b<7;++b)for(int c=0;c<7;++c) Cc[a][b][c]=0.0;
  for(int m1=-l1;m1<=l1;++m1)
    for(int m2=-l2;m2<=l2;++m2){
      int m3=m1+m2;
      if(m3>=-l3&&m3<=l3) Cc[m1+l1][m2+l2][m3+l3]=cg_coef(l1,m1,l2,m2,l3,m3);
    }
  std::complex<double> U1[7][7],U2[7][7],U3[7][7];
  u_fill(l1,U1); u_fill(l2,U2); u_fill(l3,U3);
  std::complex<double> Cr[343];
  double sre=0.0,sim=0.0;
  for(int a=0;a<n1;++a)for(int b=0;b<n2;++b)for(int c=0;c<n3;++c){
    std::complex<double> acc(0.0,0.0);
    for(int u=0;u<n1;++u)for(int v=0;v<n2;++v)for(int w=0;w<n3;++w){
      double cc=Cc[u][v][w];
      if(cc==0.0) continue;
      acc += U1[a][u]*U2[b][v]*std::conj(U3[c][w])*cc;
    }
    Cr[(a*n2+b)*n3+c]=acc;
    sre+=fabs(acc.real()); sim+=fabs(acc.imag());
  }
  bool useim = sim>sre;
  for(int idx=0;idx<n1*n2*n3;++idx) out[idx]=(float)(useim?Cr[idx].imag():Cr[idx].real());
}

static void build_cg(CGPack& P){
  cg_fill(0,0,0,P.c000);
  cg_fill(1,1,0,P.c110);
  cg_fill(2,2,0,P.c220);
  cg_fill(3,3,0,P.c330);
  cg_fill(0,1,1,P.c011);
  cg_fill(1,0,1,P.c101);
  cg_fill(1,1,1,P.c111);
  cg_fill(1,2,1,P.c121);
  cg_fill(2,1,1,P.c211);
  cg_fill(2,2,1,P.c221);
  cg_fill(2,3,1,P.c231);
  cg_fill(3,2,1,P.c321);
  cg_fill(3,3,1,P.c331);
}

// ---------------- device helpers ----------------
__device__ __forceinline__ float soh(float r, float c){
  float d = (r - c) * 2.0f;
  float d2 = d*d;
  return (d2 < 1.0f) ? 1.14136f * expf(2.0f + 1.0f/(d2-1.0f)) : 0.0f;
}

// ---------------- radial MLP lookup table: tab[T_TAB][336] ----------------
__global__ __launch_bounds__(256) void k_table(
    const float* __restrict__ W1, const float* __restrict__ W2,
    const float* __restrict__ W1f, const float* __restrict__ W2f,
    float* __restrict__ tab)
{
  __shared__ float h[G_TAB][256];
  __shared__ float hf[G_TAB][256];
  const int c = threadIdx.x;
  const int t0 = blockIdx.x * G_TAB;
  const float dr = 2.5f / (float)(T_TAB-1);
  const float w1a = W1[c], w1b = W1[256+c], w1c = W1[512+c];
  const float f1a = W1f[c], f1b = W1f[256+c], f1c = W1f[512+c];
#pragma unroll
  for (int g=0; g<G_TAB; ++g){
    float r = (float)(t0+g) * dr;
    float e0 = soh(r,1.0f), e1 = soh(r,1.5f), e2 = soh(r,2.0f);
    h[g][c]  = fmaxf(e0*w1a + e1*w1b + e2*w1c, 0.0f);
    hf[g][c] = fmaxf(e0*f1a + e1*f1b + e2*f1c, 0.0f);
  }
  __syncthreads();
  for (int j = c; j < 336; j += 256){
    float acc[G_TAB];
#pragma unroll
    for (int g=0; g<G_TAB; ++g) acc[g]=0.0f;
    if (j < 272){
      for (int cc=0; cc<256; ++cc){
        float wv = W2[cc*272 + j];
#pragma unroll
        for (int g=0; g<G_TAB; ++g) acc[g] = fmaf(h[g][cc], wv, acc[g]);
      }
    } else {
      int jj = j - 272;
      for (int cc=0; cc<256; ++cc){
        float wv = W2f[cc*64 + jj];
#pragma unroll
        for (int g=0; g<G_TAB; ++g) acc[g] = fmaf(hf[g][cc], wv, acc[g]);
      }
    }
#pragma unroll
    for (int g=0; g<G_TAB; ++g) tab[(size_t)(t0+g)*336 + j] = acc[g] * 0.0625f;
  }
}

// ---------------- rowptr: dst is globally non-decreasing -> CSR via binary search ----
__global__ __launch_bounds__(256) void k_rowptr(
    const int* __restrict__ dst, int E, int* __restrict__ rowptr)
{
  const int n = blockIdx.x*256 + threadIdx.x;
  if (n > NN) return;
  int lo=0, hi=E;
  while (lo < hi){ int mid=(lo+hi)>>1; if (dst[mid] < n) lo=mid+1; else hi=mid; }
  rowptr[n]=lo;
}

// ---------------- x = segsum(sph_harm) gather: 4 threads per node ----------------
__global__ __launch_bounds__(256) void k_x(
    const float* __restrict__ pos, const int* __restrict__ src,
    const int* __restrict__ rowptr, float* __restrict__ xacc)
{
  const int t = blockIdx.x*256 + threadIdx.x;
  const int n = t>>2, q = t&3;
  if (n>=NN) return;
  const int r0=rowptr[n], r1=rowptr[n+1];
  const float pdx=pos[3*n], pdy=pos[3*n+1], pdz=pos[3*n+2];
  const float s3=1.73205081f, s5=2.23606798f, s15=3.87298335f;
  const float c33=2.09165007f, c32=10.2469508f, c31=1.62018517f, c30=1.32287566f, cp2=5.12347538f;
  float a0=0.f,a1=0.f,a2=0.f,a3=0.f;
  for (int e=r0;e<r1;++e){
    const int s=src[e];
    float ax=pos[3*s]-pdx, ay=pos[3*s+1]-pdy, az=pos[3*s+2]-pdz;
    float ir = 1.0f/sqrtf(ax*ax+ay*ay+az*az);
    float x=ax*ir, y=ay*ir, z=az*ir;
    if (q==0){ a0+=1.0f; a1+=s3*y; a2+=s3*z; a3+=s3*x; }
    else if (q==1){ a0+=s15*x*y; a1+=s15*y*z; a2+=0.5f*s5*(3.0f*z*z-1.0f); a3+=s15*x*z; }
    else if (q==2){ a0+=0.5f*s15*(x*x-y*y); a1+=c33*y*(3.0f*x*x-y*y); a2+=c32*x*y*z; a3+=c31*y*(5.0f*z*z-1.0f); }
    else { a0+=c30*(5.0f*z*z*z-3.0f*z); a1+=c31*x*(5.0f*z*z-1.0f); a2+=cp2*z*(x*x-y*y); a3+=c33*x*(x*x-3.0f*y*y); }
  }
  *(float4*)(xacc + (size_t)n*16 + q*4) = make_float4(a0,a1,a2,a3);
}

// ---------------- fctp1 gather: 2 nodes/block, 128 threads/node ----
// Phase 1: 4 lanes/edge compute the 31 CG intermediates into LDS (balanced parts).
// Stage:   all threads cooperatively lerp the edge's 272 table weights into LDS.
// Phase 2: each output thread does np pure-LDS FMAs per edge, plain store.
__global__ __launch_bounds__(256) void k_tp1(
    const float* __restrict__ pos, const int* __restrict__ src,
    const int* __restrict__ rowptr, const float* __restrict__ xacc,
    const float* __restrict__ tab, float* __restrict__ x2, CGPack cg)
{
  const int half = threadIdx.x >> 7;
  const int c    = threadIdx.x & 127;
  const int node = blockIdx.x*2 + half;
  __shared__ float SI[2][CH][34];
  __shared__ float SW[2][CH][272];
  __shared__ int   SiT[2][CH];
  __shared__ int   sdeg[2];
  const int r0 = rowptr[node], r1 = rowptr[node+1];
  if (c==0) sdeg[half] = r1 - r0;
  __syncthreads();
  const int maxdeg = max(sdeg[0], sdeg[1]);
  const int nch = (maxdeg + CH - 1) / CH;

  // per-thread output mapping
  int wo[6], io[6], outOff, np; float scale;
  if (c < 32){
    wo[0]=c; wo[1]=64+c; wo[2]=144+c; wo[3]=224+c; wo[4]=0; wo[5]=0;
    io[0]=0; io[1]=1; io[2]=2; io[3]=3; io[4]=0; io[5]=0;
    outOff = c + (c<16 ? 0 : (c<24 ? 16 : 24));
    scale = 0.5f; np = 4;
  } else if (c < 80){
    int idx=c-32, u=idx/3, k=idx-3*u;
    wo[0]=32+u; wo[1]=48+u; wo[2]=112+u; wo[3]=128+u; wo[4]=192+u; wo[5]=208+u;
    io[0]=4+k; io[1]=7+k; io[2]=10+k; io[3]=13+k; io[4]=16+k; io[5]=19+k;
    outOff = 64+idx; scale = 0.4082482905f; np = 6;
  } else {
    int idx=c-80, u=idx/3, k=idx-3*u;
    wo[0]=96+u; wo[1]=176+u; wo[2]=256+u; wo[3]=0; wo[4]=0; wo[5]=0;
    io[0]=22+k; io[1]=25+k; io[2]=28+k; io[3]=0; io[4]=0; io[5]=0;
    outOff = 112+idx; scale = 0.5773502692f; np = 3;
  }

  const float pdx=pos[3*node], pdy=pos[3*node+1], pdz=pos[3*node+2];
  const int je   = c & (CH-1);
  const int part = c >> 4;     // 0..7, parts 0..3 active in phase 1
  float acc = 0.f;

  for (int t=0; t<nch; ++t){
    const int e0 = r0 + t*CH;
    const int cnt = min(CH, r1-e0);   // may be <= 0
    __syncthreads();                  // SI/SW reusable
    if (part < 4 && je < cnt){
      const int e = e0 + je;
      const int s = src[e];
      float ax=pos[3*s]-pdx, ay=pos[3*s+1]-pdy, az=pos[3*s+2]-pdz;
      float r = sqrtf(ax*ax+ay*ay+az*az);
      float ir = 1.0f/r;
      float x=ax*ir, y=ay*ir, z=az*ir;

      const float s3=1.73205081f, s5=2.23606798f, s15=3.87298335f;
      const float c33=2.09165007f, c32=10.2469508f, c31=1.62018517f, c30=1.32287566f, cp2=5.12347538f;
      float Y[16];
      Y[0]=1.0f;
      Y[1]=s3*y; Y[2]=s3*z; Y[3]=s3*x;
      Y[4]=s15*x*y; Y[5]=s15*y*z; Y[6]=0.5f*s5*(3.0f*z*z-1.0f); Y[7]=s15*x*z; Y[8]=0.5f*s15*(x*x-y*y);
      Y[9]=c33*y*(3.0f*x*x-y*y); Y[10]=c32*x*y*z; Y[11]=c31*y*(5.0f*z*z-1.0f);
      Y[12]=c30*(5.0f*z*z*z-3.0f*z); Y[13]=c31*x*(5.0f*z*z-1.0f); Y[14]=cp2*z*(x*x-y*y);
      Y[15]=c33*x*(x*x-3.0f*y*y);
      float X[16];
      {
        const float inv = 0.5129891760f;           // 1/sqrt(3.8)
        const float4* q4 = (const float4*)(xacc + (size_t)s*16);
        float4 a=q4[0],b=q4[1],cc4=q4[2],d4=q4[3];
        X[0]=a.x*inv;X[1]=a.y*inv;X[2]=a.z*inv;X[3]=a.w*inv;
        X[4]=b.x*inv;X[5]=b.y*inv;X[6]=b.z*inv;X[7]=b.w*inv;
        X[8]=cc4.x*inv;X[9]=cc4.y*inv;X[10]=cc4.z*inv;X[11]=cc4.w*inv;
        X[12]=d4.x*inv;X[13]=d4.y*inv;X[14]=d4.z*inv;X[15]=d4.w*inv;
      }
      float* SS = SI[half][je];

      if (part == 0){
        // t0..t3 + v12 + (i0, al)
        float f = r * 1638.0f;
        int i0 = (int)f; if (i0 > T_TAB-2) i0 = T_TAB-2;
        float al = f - (float)i0;
        float t0v = cg.c000[0]*X[0]*Y[0];
        float t1v=0.f, t2v=0.f, t3v=0.f;
#pragma unroll
        for (int i=0;i<3;++i)
#pragma unroll
          for (int j=0;j<3;++j) t1v = fmaf(X[1+i]*Y[1+j], cg.c110[i*3+j], t1v);
#pragma unroll
        for (int i=0;i<5;++i)
#pragma unroll
          for (int j=0;j<5;++j) t2v = fmaf(X[4+i]*Y[4+j], cg.c220[i*5+j], t2v);
#pragma unroll
        for (int i=0;i<7;++i)
#pragma unroll
          for (int j=0;j<7;++j) t3v = fmaf(X[9+i]*Y[9+j], cg.c330[i*7+j], t3v);
        float v12[3]={0,0,0};
#pragma unroll
        for (int i=0;i<3;++i)
#pragma unroll
          for (int j=0;j<5;++j){ float tt=X[1+i]*Y[4+j];
#pragma unroll
            for (int k=0;k<3;++k) v12[k]=fmaf(tt, cg.c121[(i*5+j)*3+k], v12[k]); }
        SS[0]=t0v; SS[1]=t1v; SS[2]=t2v; SS[3]=t3v;
        SS[10]=v12[0]; SS[11]=v12[1]; SS[12]=v12[2];
        SS[32]=al;
        SiT[half][je]=i0;
      } else if (part == 1){
        // v01, v10, v33
        float v01[3]={0,0,0}, v10[3]={0,0,0}, v33[3]={0,0,0};
#pragma unroll
        for (int j=0;j<3;++j){ float tt=X[0]*Y[1+j];
#pragma unroll
          for (int k=0;k<3;++k) v01[k]=fmaf(tt, cg.c011[j*3+k], v01[k]); }
#pragma unroll
        for (int i=0;i<3;++i){ float tt=X[1+i]*Y[0];
#pragma unroll
          for (int k=0;k<3;++k) v10[k]=fmaf(tt, cg.c101[i*3+k], v10[k]); }
#pragma unroll
        for (int i=0;i<7;++i)
#pragma unroll
          for (int j=0;j<7;++j){ float tt=X[9+i]*Y[9+j];
#pragma unroll
            for (int k=0;k<3;++k) v33[k]=fmaf(tt, cg.c331[(i*7+j)*3+k], v33[k]); }
        SS[4]=v01[0]; SS[5]=v01[1]; SS[6]=v01[2];
        SS[7]=v10[0]; SS[8]=v10[1]; SS[9]=v10[2];
        SS[28]=v33[0]; SS[29]=v33[1]; SS[30]=v33[2];
      } else if (part == 2){
        // v11, v21, v23
        float v11[3]={0,0,0}, v21[3]={0,0,0}, v23[3]={0,0,0};
#pragma unroll
        for (int i=0;i<3;++i)
#pragma unroll
          for (int j=0;j<3;++j){ float tt=X[1+i]*Y[1+j];
#pragma unroll
            for (int k=0;k<3;++k) v11[k]=fmaf(tt, cg.c111[(i*3+j)*3+k], v11[k]); }
#pragma unroll
        for (int i=0;i<5;++i)
#pragma unroll
          for (int j=0;j<3;++j){ float tt=X[4+i]*Y[1+j];
#pragma unroll
            for (int k=0;k<3;++k) v21[k]=fmaf(tt, cg.c211[(i*3+j)*3+k], v21[k]); }
#pragma unroll
        for (int i=0;i<5;++i)
#pragma unroll
          for (int j=0;j<7;++j){ float tt=X[4+i]*Y[9+j];
#pragma unroll
            for (int k=0;k<3;++k) v23[k]=fmaf(tt, cg.c231[(i*7+j)*3+k], v23[k]); }
        SS[22]=v11[0]; SS[23]=v11[1]; SS[24]=v11[2];
        SS[13]=v21[0]; SS[14]=v21[1]; SS[15]=v21[2];
        SS[16]=v23[0]; SS[17]=v23[1]; SS[18]=v23[2];
      } else {
        // v22, v32
        float v22[3]={0,0,0}, v32[3]={0,0,0};
#pragma unroll
        for (int i=0;i<5;++i)
#pragma unroll
          for (int j=0;j<5;++j){ float tt=X[4+i]*Y[4+j];
#pragma unroll
            for (int k=0;k<3;++k) v22[k]=fmaf(tt, cg.c221[(i*5+j)*3+k], v22[k]); }
#pragma unroll
        for (int i=0;i<7;++i)
#pragma unroll
          for (int j=0;j<5;++j){ float tt=X[9+i]*Y[4+j];
#pragma unroll
            for (int k=0;k<3;++k) v32[k]=fmaf(tt, cg.c321[(i*5+j)*3+k], v32[k]); }
        SS[25]=v22[0]; SS[26]=v22[1]; SS[27]=v22[2];
        SS[19]=v32[0]; SS[20]=v32[1]; SS[21]=v32[2];
      }
    }
    __syncthreads();
    // ---- stage lerped weight rows into LDS (coalesced, deduped) ----
#pragma unroll 4
    for (int e=0; e<CH; ++e){
      if (e < cnt){
        const float al = SI[half][e][32];
        const float* __restrict__ w0 = tab + (size_t)SiT[half][e]*336;
        const float* __restrict__ w1 = w0 + 336;
        float* __restrict__ dw = SW[half][e];
        int o = c;
        dw[o] = fmaf(al, w1[o]-w0[o], w0[o]);
        o = 128 + c;
        dw[o] = fmaf(al, w1[o]-w0[o], w0[o]);
        if (c < 16){ o = 256 + c; dw[o] = fmaf(al, w1[o]-w0[o], w0[o]); }
      }
    }
    __syncthreads();
    // ---- phase 2: pure-LDS accumulate ----
#pragma unroll 4
    for (int j=0; j<CH; ++j){
      if (j < cnt){
        const float* __restrict__ I = SI[half][j];
        const float* __restrict__ W = SW[half][j];
        for (int p=0; p<np; ++p)
          acc = fmaf(W[wo[p]], I[io[p]], acc);
      }
    }
  }
  x2[(size_t)node*160 + outOff] = scale*acc;
}

// ---------------- gate ----------------
__global__ __launch_bounds__(256) void k_gate(
    const float* __restrict__ x2, float* __restrict__ xg, int N)
{
  const int n = blockIdx.x*256 + threadIdx.x;
  if (n>=N) return;
  const float* __restrict__ x = x2 + (size_t)n*160;
  float* __restrict__ g = xg + (size_t)n*128;
  const float inv = 0.5129891760f;
  float gg[16], gh[16];
#pragma unroll
  for (int u=0;u<8;++u){
    gg[u]   = fmaxf(x[32+u]*inv, 0.0f);
    gg[8+u] = tanhf(x[40+u]*inv);
    gh[u]   = fmaxf(x[48+u]*inv, 0.0f);
    gh[8+u] = tanhf(x[56+u]*inv);
  }
#pragma unroll
  for (int i=0;i<16;++i) g[i]    = fmaxf(x[i]*inv, 0.0f);
#pragma unroll
  for (int i=0;i<16;++i) g[16+i] = fabsf(x[16+i]*inv);
#pragma unroll
  for (int u=0;u<16;++u)
#pragma unroll
    for (int k=0;k<3;++k){
      g[32+u*3+k] = x[64+u*3+k]*inv*gg[u];
      g[80+u*3+k] = x[112+u*3+k]*inv*gh[u];
    }
}

// ---------------- fctp2 per edge -> e2buf[E][4] ----------------
__global__ __launch_bounds__(256) void k_tp2(
    const float* __restrict__ pos, const int* __restrict__ src, const int* __restrict__ dst, int E,
    const float* __restrict__ xg, const float* __restrict__ tab,
    float* __restrict__ e2buf, CGPack cg)
{
  const int e = blockIdx.x*256 + threadIdx.x;
  if (e>=E) return;
  const int s = src[e], d = dst[e];
  float ax=pos[3*s]-pos[3*d], ay=pos[3*s+1]-pos[3*d+1], az=pos[3*s+2]-pos[3*d+2];
  float r = sqrtf(ax*ax+ay*ay+az*az);
  float ir = 1.0f/r;
  float x=ax*ir, y=ay*ir, z=az*ir;
  float f = r * 1638.0f;
  int i0 = (int)f; if (i0 > T_TAB-2) i0 = T_TAB-2;
  const float al = f - (float)i0;
  const float* __restrict__ w0 = tab + (size_t)i0*336 + 272;
  const float* __restrict__ w1 = w0 + 336;
  float wf[64];
#pragma unroll
  for (int j=0;j<64;j+=4){
    float4 p = *(const float4*)(w0+j);
    float4 q = *(const float4*)(w1+j);
    wf[j+0]=fmaf(al,q.x-p.x,p.x);
    wf[j+1]=fmaf(al,q.y-p.y,p.y);
    wf[j+2]=fmaf(al,q.z-p.z,p.z);
    wf[j+3]=fmaf(al,q.w-p.w,p.w);
  }
  const float s3=1.73205081f, s5=2.23606798f, s15=3.87298335f;
  float Y[16];
  Y[0]=1.0f;
  Y[1]=s3*y; Y[2]=s3*z; Y[3]=s3*x;
  Y[4]=s15*x*y; Y[5]=s15*y*z; Y[6]=0.5f*s5*(3.0f*z*z-1.0f); Y[7]=s15*x*z; Y[8]=0.5f*s15*(x*x-y*y);
  const float* __restrict__ g = xg + (size_t)s*128;
  float se[16], vo[48], ve[48];
#pragma unroll
  for (int jj=0;jj<4;++jj){ float4 t=((const float4*)g)[jj];
    se[4*jj]=t.x; se[4*jj+1]=t.y; se[4*jj+2]=t.z; se[4*jj+3]=t.w; }
#pragma unroll
  for (int jj=0;jj<12;++jj){ float4 t=((const float4*)(g+32))[jj];
    vo[4*jj]=t.x; vo[4*jj+1]=t.y; vo[4*jj+2]=t.z; vo[4*jj+3]=t.w; }
#pragma unroll
  for (int jj=0;jj<12;++jj){ float4 t=((const float4*)(g+80))[jj];
    ve[4*jj]=t.x; ve[4*jj+1]=t.y; ve[4*jj+2]=t.z; ve[4*jj+3]=t.w; }

  float SA=0.0f;
#pragma unroll
  for (int u=0;u<16;++u) SA = fmaf(wf[u], se[u], SA);
  float AB[3]={0,0,0}, AC[3]={0,0,0}, AD[3]={0,0,0};
#pragma unroll
  for (int u=0;u<16;++u)
#pragma unroll
    for (int i=0;i<3;++i){
      AB[i]=fmaf(wf[16+u], vo[u*3+i], AB[i]);
      AC[i]=fmaf(wf[32+u], vo[u*3+i], AC[i]);
      AD[i]=fmaf(wf[48+u], ve[u*3+i], AD[i]);
    }
  float e2[3]={0,0,0};
#pragma unroll
  for (int j=0;j<3;++j){ float t=SA*Y[1+j];
#pragma unroll
    for (int k=0;k<3;++k) e2[k]=fmaf(t, cg.c011[j*3+k], e2[k]); }
#pragma unroll
  for (int i=0;i<3;++i){ float t=AB[i]*Y[0];
#pragma unroll
    for (int k=0;k<3;++k) e2[k]=fmaf(t, cg.c101[i*3+k], e2[k]); }
#pragma unroll
  for (int i=0;i<3;++i)
#pragma unroll
    for (int j=0;j<5;++j){ float t=AC[i]*Y[4+j];
#pragma unroll
      for (int k=0;k<3;++k) e2[k]=fmaf(t, cg.c121[(i*5+j)*3+k], e2[k]); }
#pragma unroll
  for (int i=0;i<3;++i)
#pragma unroll
    for (int j=0;j<3;++j){ float t=AD[i]*Y[1+j];
#pragma unroll
      for (int k=0;k<3;++k) e2[k]=fmaf(t, cg.c111[(i*3+j)*3+k], e2[k]); }

  *(float4*)(e2buf + (size_t)e*4) = make_float4(e2[0], e2[1], e2[2], 0.0f);
}

// ---------------- final gather: out[n] = sc * sum(e2buf over incoming edges) -------
__global__ __launch_bounds__(256) void k_out(
    const float* __restrict__ e2buf, const int* __restrict__ rowptr,
    float* __restrict__ out)
{
  const int t = blockIdx.x*256 + threadIdx.x;
  const int n = t>>2, k = t&3;
  if (n>=NN) return;
  const int r0=rowptr[n], r1=rowptr[n+1];
  float a=0.f;
  for (int e=r0;e<r1;++e) a += e2buf[(size_t)e*4 + k];
  const float sc = 0.0641236437f;  // (1/sqrt(64)) * 1/sqrt(3.8)
  if (k<3) out[(size_t)n*3 + k] = a*sc;
}

// ---------------- host launcher ----------------
extern "C" void kernel_launch(void* const* d_in, const int* in_sizes, int n_in,
                              void* d_out, int out_size, void* d_ws, size_t ws_size,
                              hipStream_t stream)
{
  (void)n_in; (void)ws_size; (void)out_size;
  const float* pos = (const float*)d_in[0];
  const int*   src = (const int*)d_in[1];
  const int*   dst = (const int*)d_in[2];
  const float* W1  = (const float*)d_in[3];
  const float* W2  = (const float*)d_in[4];
  const float* W1f = (const float*)d_in[5];
  const float* W2f = (const float*)d_in[6];
  const int E = in_sizes[1];

  char* ws = (char*)d_ws;
  float* xacc  = (float*)ws;                     // NN*16
  float* x2    = xacc + (size_t)NN*16;           // NN*160
  float* xg    = x2 + (size_t)NN*160;            // NN*128
  float* tab   = xg + (size_t)NN*128;            // T_TAB*336
  float* e2buf = tab + (size_t)T_TAB*336;        // E*4
  int*   rowptr= (int*)(e2buf + (size_t)E*4);    // NN+1

  CGPack cg;
  build_cg(cg);

  k_table<<<T_TAB/G_TAB, 256, 0, stream>>>(W1, W2, W1f, W2f, tab);
  k_rowptr<<<(NN+1+255)/256, 256, 0, stream>>>(dst, E, rowptr);
  k_x<<<(NN*4)/256, 256, 0, stream>>>(pos, src, rowptr, xacc);
  k_tp1<<<NN/2, 256, 0, stream>>>(pos, src, rowptr, xacc, tab, x2, cg);
  k_gate<<<(NN + 255) / 256, 256, 0, stream>>>(x2, xg, NN);
  k_tp2<<<(E + 255) / 256, 256, 0, stream>>>(pos, src, dst, E, xg, tab, e2buf, cg);
  k_out<<<(NN*4)/256, 256, 0, stream>>>(e2buf, rowptr, (float*)d_out);
}

// Round 4
// 249.606 us; speedup vs baseline: 1.9525x; 1.9525x over previous
//
#include <hip/hip_runtime.h>
#include <cmath>
#include <complex>

#define T_TAB 4096
#define G_TAB 8
#define NN 16384
#define CH 16

// ---------------- CG tables (exact host-side port of the reference) ----------------
struct CGPack {
  float c000[1];
  float c110[9];
  float c220[25];
  float c330[49];
  float c011[9];
  float c101[9];
  float c111[27];
  float c121[45];
  float c211[45];
  float c221[75];
  float c231[105];
  float c321[105];
  float c331[147];
};

static double factd(int n){ double r=1.0; for(int i=2;i<=n;++i) r*=(double)i; return r; }

static double cg_coef(int j1,int m1,int j2,int m2,int j3,int m3){
  double pref = sqrt((2.0*j3+1.0)*factd(j3+j1-j2)*factd(j3-j1+j2)*factd(j1+j2-j3)/factd(j1+j2+j3+1));
  pref *= sqrt(factd(j3+m3)*factd(j3-m3)*factd(j1-m1)*factd(j1+m1)*factd(j2-m2)*factd(j2+m2));
  double s=0.0;
  for(int k=0;k<=j1+j2-j3;++k){
    int a0=k,a1=j1+j2-j3-k,a2=j1-m1-k,a3=j2+m2-k,a4=j3-j2+m1+k,a5=j3-j1-m2+k;
    if(a0<0||a1<0||a2<0||a3<0||a4<0||a5<0) continue;
    double d=factd(a0)*factd(a1)*factd(a2)*factd(a3)*factd(a4)*factd(a5);
    s += ((k&1)?-1.0:1.0)/d;
  }
  return pref*s;
}

static void u_fill(int l, std::complex<double> U[7][7]){
  for(int i=0;i<7;++i) for(int j=0;j<7;++j) U[i][j]=std::complex<double>(0.0,0.0);
  const double is2 = 1.0/sqrt(2.0);
  U[l][l]=1.0;
  for(int m=1;m<=l;++m){
    double sgn = (m&1)?-1.0:1.0;
    U[l+m][l+m] = sgn*is2;
    U[l+m][l-m] = is2;
    U[l-m][l-m] = std::complex<double>(0.0, is2);
    U[l-m][l+m] = std::complex<double>(0.0, -sgn*is2);
  }
}

static void cg_fill(int l1,int l2,int l3, float* out){
  int n1=2*l1+1,n2=2*l2+1,n3=2*l3+1;
  double Cc[7][7][7];
  for(int a=0;a<7;++a)for(int b=0;b<7;++b)for(int c=0;c<7;++c) Cc[a][b][c]=0.0;
  for(int m1=-l1;m1<=l1;++m1)
    for(int m2=-l2;m2<=l2;++m2){
      int m3=m1+m2;
      if(m3>=-l3&&m3<=l3) Cc[m1+l1][m2+l2][m3+l3]=cg_coef(l1,m1,l2,m2,l3,m3);
    }
  std::complex<double> U1[7][7],U2[7][7],U3[7][7];
  u_fill(l1,U1); u_fill(l2,U2); u_fill(l3,U3);
  std::complex<double> Cr[343];
  double sre=0.0,sim=0.0;
  for(int a=0;a<n1;++a)for(int b=0;b<n2;++b)for(int c=0;c<n3;++c){
    std::complex<double> acc(0.0,0.0);
    for(int u=0;u<n1;++u)for(int v=0;v<n2;++v)for(int w=0;w<n3;++w){
      double cc=Cc[u][v][w];
      if(cc==0.0) continue;
      acc += U1[a][u]*U2[b][v]*std::conj(U3[c][w])*cc;
    }
    Cr[(a*n2+b)*n3+c]=acc;
    sre+=fabs(acc.real()); sim+=fabs(acc.imag());
  }
  bool useim = sim>sre;
  for(int idx=0;idx<n1*n2*n3;++idx) out[idx]=(float)(useim?Cr[idx].imag():Cr[idx].real());
}

static void build_cg(CGPack& P){
  cg_fill(0,0,0,P.c000);
  cg_fill(1,1,0,P.c110);
  cg_fill(2,2,0,P.c220);
  cg_fill(3,3,0,P.c330);
  cg_fill(0,1,1,P.c011);
  cg_fill(1,0,1,P.c101);
  cg_fill(1,1,1,P.c111);
  cg_fill(1,2,1,P.c121);
  cg_fill(2,1,1,P.c211);
  cg_fill(2,2,1,P.c221);
  cg_fill(2,3,1,P.c231);
  cg_fill(3,2,1,P.c321);
  cg_fill(3,3,1,P.c331);
}

// ---------------- device helpers ----------------
__device__ __forceinline__ float soh(float r, float c){
  float d = (r - c) * 2.0f;
  float d2 = d*d;
  return (d2 < 1.0f) ? 1.14136f * expf(2.0f + 1.0f/(d2-1.0f)) : 0.0f;
}

// ---------------- radial MLP lookup table: tab[T_TAB][336] ----------------
__global__ __launch_bounds__(256) void k_table(
    const float* __restrict__ W1, const float* __restrict__ W2,
    const float* __restrict__ W1f, const float* __restrict__ W2f,
    float* __restrict__ tab)
{
  __shared__ float h[G_TAB][256];
  __shared__ float hf[G_TAB][256];
  const int c = threadIdx.x;
  const int t0 = blockIdx.x * G_TAB;
  const float dr = 2.5f / (float)(T_TAB-1);
  const float w1a = W1[c], w1b = W1[256+c], w1c = W1[512+c];
  const float f1a = W1f[c], f1b = W1f[256+c], f1c = W1f[512+c];
#pragma unroll
  for (int g=0; g<G_TAB; ++g){
    float r = (float)(t0+g) * dr;
    float e0 = soh(r,1.0f), e1 = soh(r,1.5f), e2 = soh(r,2.0f);
    h[g][c]  = fmaxf(e0*w1a + e1*w1b + e2*w1c, 0.0f);
    hf[g][c] = fmaxf(e0*f1a + e1*f1b + e2*f1c, 0.0f);
  }
  __syncthreads();
  for (int j = c; j < 336; j += 256){
    float acc[G_TAB];
#pragma unroll
    for (int g=0; g<G_TAB; ++g) acc[g]=0.0f;
    if (j < 272){
      for (int cc=0; cc<256; ++cc){
        float wv = W2[cc*272 + j];
#pragma unroll
        for (int g=0; g<G_TAB; ++g) acc[g] = fmaf(h[g][cc], wv, acc[g]);
      }
    } else {
      int jj = j - 272;
      for (int cc=0; cc<256; ++cc){
        float wv = W2f[cc*64 + jj];
#pragma unroll
        for (int g=0; g<G_TAB; ++g) acc[g] = fmaf(hf[g][cc], wv, acc[g]);
      }
    }
#pragma unroll
    for (int g=0; g<G_TAB; ++g) tab[(size_t)(t0+g)*336 + j] = acc[g] * 0.0625f;
  }
}

// ---------------- rowptr: dst is globally non-decreasing -> CSR via binary search ----
__global__ __launch_bounds__(256) void k_rowptr(
    const int* __restrict__ dst, int E, int* __restrict__ rowptr)
{
  const int n = blockIdx.x*256 + threadIdx.x;
  if (n > NN) return;
  int lo=0, hi=E;
  while (lo < hi){ int mid=(lo+hi)>>1; if (dst[mid] < n) lo=mid+1; else hi=mid; }
  rowptr[n]=lo;
}

// ---------------- x = segsum(sph_harm): 4 lanes/node, each edge touched once -------
__global__ __launch_bounds__(256) void k_x(
    const float* __restrict__ pos, const int* __restrict__ src,
    const int* __restrict__ rowptr, float* __restrict__ xacc)
{
  const int t = blockIdx.x*256 + threadIdx.x;
  const int n = t>>2, q = t&3;
  if (n>=NN) return;
  const int r0=rowptr[n], r1=rowptr[n+1];
  const float pdx=pos[3*n], pdy=pos[3*n+1], pdz=pos[3*n+2];
  const float s3=1.73205081f, s5=2.23606798f, s15=3.87298335f;
  const float c33=2.09165007f, c32=10.2469508f, c31=1.62018517f, c30=1.32287566f, cp2=5.12347538f;
  float a0=0,a1=0,a2=0,a3=0,a4=0,a5=0,a6=0,a7=0,a8=0,a9=0,a10=0,a11=0,a12=0,a13=0,a14=0,a15=0;
  for (int e=r0+q; e<r1; e+=4){
    const int s=src[e];
    float ax=pos[3*s]-pdx, ay=pos[3*s+1]-pdy, az=pos[3*s+2]-pdz;
    float ir = 1.0f/sqrtf(ax*ax+ay*ay+az*az);
    float x=ax*ir, y=ay*ir, z=az*ir;
    a0+=1.0f; a1+=s3*y; a2+=s3*z; a3+=s3*x;
    a4+=s15*x*y; a5+=s15*y*z; a6+=0.5f*s5*(3.0f*z*z-1.0f); a7+=s15*x*z;
    a8+=0.5f*s15*(x*x-y*y); a9+=c33*y*(3.0f*x*x-y*y); a10+=c32*x*y*z; a11+=c31*y*(5.0f*z*z-1.0f);
    a12+=c30*(5.0f*z*z*z-3.0f*z); a13+=c31*x*(5.0f*z*z-1.0f); a14+=cp2*z*(x*x-y*y);
    a15+=c33*x*(x*x-3.0f*y*y);
  }
#define RED(v) v += __shfl_xor(v,1); v += __shfl_xor(v,2);
  RED(a0) RED(a1) RED(a2) RED(a3) RED(a4) RED(a5) RED(a6) RED(a7)
  RED(a8) RED(a9) RED(a10) RED(a11) RED(a12) RED(a13) RED(a14) RED(a15)
#undef RED
  float o0,o1,o2,o3;
  if (q==0){ o0=a0; o1=a1; o2=a2; o3=a3; }
  else if (q==1){ o0=a4; o1=a5; o2=a6; o3=a7; }
  else if (q==2){ o0=a8; o1=a9; o2=a10; o3=a11; }
  else { o0=a12; o1=a13; o2=a14; o3=a15; }
  *(float4*)(xacc + (size_t)n*16 + q*4) = make_float4(o0,o1,o2,o3);
}

// ---------------- fctp1 + gate fused: one wave per node ----------------
// Phase 1: 4 lanes/edge -> 31 CG intermediates, stored as I*(1-al), I*al in LDS.
// Phase 2: uniform 8x(weight,slot) register schedule, 2 accs/lane, direct tab loads.
// Epilogue: gate via 32-float LDS exchange; writes compact xg[NN][64].
__global__ __launch_bounds__(128) void k_tp1(
    const float* __restrict__ pos, const int* __restrict__ src,
    const int* __restrict__ rowptr, const float* __restrict__ xacc,
    const float* __restrict__ tab, float* __restrict__ xg, CGPack cg)
{
  const int half = threadIdx.x >> 6;
  const int lane = threadIdx.x & 63;
  const int node = blockIdx.x*2 + half;
  __shared__ float SIA[2][CH][32];
  __shared__ float SIB[2][CH][32];
  __shared__ int   SiT[2][CH];
  __shared__ float SG[2][32];
  __shared__ int   sdeg[2];
  const int r0 = rowptr[node], r1 = rowptr[node+1];
  if (lane==0) sdeg[half] = r1 - r0;
  __syncthreads();
  const int nch = (max(sdeg[0],sdeg[1]) + CH - 1) / CH;

  // ---- uniform per-lane schedule: 8 (weight-offset, LDS-slot) pairs, 2 accs ----
  int wo[8], ioS[8];
#pragma unroll
  for (int p=0;p<8;++p){ wo[p]=0; ioS[p]=31; }   // dummies: weight 0 x zero-slot
  int gu0=16, gu1=16;                            // gate indices into SG
  if (lane < 16){
#pragma unroll
    for (int s=0;s<2;++s){
      int a = 2*lane+s;
      int b0,b1,b2,b3;
      if (a<16){ b0=a; b1=64+a; b2=144+a; b3=224+a; }
      else if (a<24){ int u=a-16; b0=16+u; b1=80+u; b2=160+u; b3=240+u; }
      else { int u=a-24; b0=24+u; b1=88+u; b2=168+u; b3=248+u; }
      wo[4*s+0]=b0; ioS[4*s+0]=0;
      wo[4*s+1]=b1; ioS[4*s+1]=1;
      wo[4*s+2]=b2; ioS[4*s+2]=2;
      wo[4*s+3]=b3; ioS[4*s+3]=3;
    }
  } else if (lane < 40){
    int idx=lane-16, u=idx/3, k=idx-3*u;
    wo[0]=32+u;  ioS[0]=4+k;    // v01
    wo[1]=48+u;  ioS[1]=7+k;    // v10
    wo[2]=112+u; ioS[2]=10+k;   // v12
    wo[3]=128+u; ioS[3]=13+k;   // v21
    wo[4]=192+u; ioS[4]=16+k;   // v23
    wo[5]=208+u; ioS[5]=19+k;   // v32
    gu0 = 16+u;
  } else if (lane < 52){
    int m=lane-40;
    int c0=2*m,   u0=c0/3, k0=c0-3*u0;
    int c1=2*m+1, u1=c1/3, k1=c1-3*u1;
    wo[0]=96+u0;  ioS[0]=22+k0;  // v11
    wo[1]=176+u0; ioS[1]=25+k0;  // v22
    wo[2]=256+u0; ioS[2]=28+k0;  // v33
    wo[4]=96+u1;  ioS[4]=22+k1;
    wo[5]=176+u1; ioS[5]=25+k1;
    wo[6]=256+u1; ioS[6]=28+k1;
    gu0 = 24+u0; gu1 = 24+u1;
  }

  const float pdx=pos[3*node], pdy=pos[3*node+1], pdz=pos[3*node+2];
  const int je = lane & 15, part = lane >> 4;
  float acc0 = 0.f, acc1 = 0.f;

  for (int t=0; t<nch; ++t){
    const int e0 = r0 + t*CH;
    const int cnt = min(CH, r1-e0);
    __syncthreads();
    if (je < cnt){
      const int e = e0 + je;
      const int s = src[e];
      float ax=pos[3*s]-pdx, ay=pos[3*s+1]-pdy, az=pos[3*s+2]-pdz;
      float r = sqrtf(ax*ax+ay*ay+az*az);
      float ir = 1.0f/r;
      float x=ax*ir, y=ay*ir, z=az*ir;
      float f = r * 1638.0f;                    // (T_TAB-1)/2.5
      int i0 = (int)f; if (i0 > T_TAB-2) i0 = T_TAB-2;
      float bl = f - (float)i0;
      float aw = 1.0f - bl;

      const float s3=1.73205081f, s5=2.23606798f, s15=3.87298335f;
      const float c33=2.09165007f, c32=10.2469508f, c31=1.62018517f, c30=1.32287566f, cp2=5.12347538f;
      float Y[16];
      Y[0]=1.0f;
      Y[1]=s3*y; Y[2]=s3*z; Y[3]=s3*x;
      Y[4]=s15*x*y; Y[5]=s15*y*z; Y[6]=0.5f*s5*(3.0f*z*z-1.0f); Y[7]=s15*x*z; Y[8]=0.5f*s15*(x*x-y*y);
      Y[9]=c33*y*(3.0f*x*x-y*y); Y[10]=c32*x*y*z; Y[11]=c31*y*(5.0f*z*z-1.0f);
      Y[12]=c30*(5.0f*z*z*z-3.0f*z); Y[13]=c31*x*(5.0f*z*z-1.0f); Y[14]=cp2*z*(x*x-y*y);
      Y[15]=c33*x*(x*x-3.0f*y*y);
      float X[16];
      {
        const float inv = 0.5129891760f;           // 1/sqrt(3.8)
        const float4* q4 = (const float4*)(xacc + (size_t)s*16);
        float4 a=q4[0],b=q4[1],cc4=q4[2],d4=q4[3];
        X[0]=a.x*inv;X[1]=a.y*inv;X[2]=a.z*inv;X[3]=a.w*inv;
        X[4]=b.x*inv;X[5]=b.y*inv;X[6]=b.z*inv;X[7]=b.w*inv;
        X[8]=cc4.x*inv;X[9]=cc4.y*inv;X[10]=cc4.z*inv;X[11]=cc4.w*inv;
        X[12]=d4.x*inv;X[13]=d4.y*inv;X[14]=d4.z*inv;X[15]=d4.w*inv;
      }
      float* A_ = SIA[half][je];
      float* B_ = SIB[half][je];
#define PUT(slot, val) { float vv_=(val); A_[slot]=vv_*aw; B_[slot]=vv_*bl; }
      if (part == 0){
        float t0v = cg.c000[0]*X[0]*Y[0];
        float t1v=0.f, t2v=0.f, t3v=0.f;
#pragma unroll
        for (int i=0;i<3;++i)
#pragma unroll
          for (int j=0;j<3;++j) t1v = fmaf(X[1+i]*Y[1+j], cg.c110[i*3+j], t1v);
#pragma unroll
        for (int i=0;i<5;++i)
#pragma unroll
          for (int j=0;j<5;++j) t2v = fmaf(X[4+i]*Y[4+j], cg.c220[i*5+j], t2v);
#pragma unroll
        for (int i=0;i<7;++i)
#pragma unroll
          for (int j=0;j<7;++j) t3v = fmaf(X[9+i]*Y[9+j], cg.c330[i*7+j], t3v);
        float v12[3]={0,0,0};
#pragma unroll
        for (int i=0;i<3;++i)
#pragma unroll
          for (int j=0;j<5;++j){ float tt=X[1+i]*Y[4+j];
#pragma unroll
            for (int k=0;k<3;++k) v12[k]=fmaf(tt, cg.c121[(i*5+j)*3+k], v12[k]); }
        PUT(0,t0v) PUT(1,t1v) PUT(2,t2v) PUT(3,t3v)
        PUT(10,v12[0]) PUT(11,v12[1]) PUT(12,v12[2])
        A_[31]=0.0f; B_[31]=0.0f;
        SiT[half][je]=i0;
      } else if (part == 1){
        float v01[3]={0,0,0}, v10[3]={0,0,0}, v33[3]={0,0,0};
#pragma unroll
        for (int j=0;j<3;++j){ float tt=X[0]*Y[1+j];
#pragma unroll
          for (int k=0;k<3;++k) v01[k]=fmaf(tt, cg.c011[j*3+k], v01[k]); }
#pragma unroll
        for (int i=0;i<3;++i){ float tt=X[1+i]*Y[0];
#pragma unroll
          for (int k=0;k<3;++k) v10[k]=fmaf(tt, cg.c101[i*3+k], v10[k]); }
#pragma unroll
        for (int i=0;i<7;++i)
#pragma unroll
          for (int j=0;j<7;++j){ float tt=X[9+i]*Y[9+j];
#pragma unroll
            for (int k=0;k<3;++k) v33[k]=fmaf(tt, cg.c331[(i*7+j)*3+k], v33[k]); }
        PUT(4,v01[0]) PUT(5,v01[1]) PUT(6,v01[2])
        PUT(7,v10[0]) PUT(8,v10[1]) PUT(9,v10[2])
        PUT(28,v33[0]) PUT(29,v33[1]) PUT(30,v33[2])
      } else if (part == 2){
        float v11[3]={0,0,0}, v21[3]={0,0,0}, v23[3]={0,0,0};
#pragma unroll
        for (int i=0;i<3;++i)
#pragma unroll
          for (int j=0;j<3;++j){ float tt=X[1+i]*Y[1+j];
#pragma unroll
            for (int k=0;k<3;++k) v11[k]=fmaf(tt, cg.c111[(i*3+j)*3+k], v11[k]); }
#pragma unroll
        for (int i=0;i<5;++i)
#pragma unroll
          for (int j=0;j<3;++j){ float tt=X[4+i]*Y[1+j];
#pragma unroll
            for (int k=0;k<3;++k) v21[k]=fmaf(tt, cg.c211[(i*3+j)*3+k], v21[k]); }
#pragma unroll
        for (int i=0;i<5;++i)
#pragma unroll
          for (int j=0;j<7;++j){ float tt=X[4+i]*Y[9+j];
#pragma unroll
            for (int k=0;k<3;++k) v23[k]=fmaf(tt, cg.c231[(i*7+j)*3+k], v23[k]); }
        PUT(22,v11[0]) PUT(23,v11[1]) PUT(24,v11[2])
        PUT(13,v21[0]) PUT(14,v21[1]) PUT(15,v21[2])
        PUT(16,v23[0]) PUT(17,v23[1]) PUT(18,v23[2])
      } else {
        float v22[3]={0,0,0}, v32[3]={0,0,0};
#pragma unroll
        for (int i=0;i<5;++i)
#pragma unroll
          for (int j=0;j<5;++j){ float tt=X[4+i]*Y[4+j];
#pragma unroll
            for (int k=0;k<3;++k) v22[k]=fmaf(tt, cg.c221[(i*5+j)*3+k], v22[k]); }
#pragma unroll
        for (int i=0;i<7;++i)
#pragma unroll
          for (int j=0;j<5;++j){ float tt=X[9+i]*Y[4+j];
#pragma unroll
            for (int k=0;k<3;++k) v32[k]=fmaf(tt, cg.c321[(i*5+j)*3+k], v32[k]); }
        PUT(25,v22[0]) PUT(26,v22[1]) PUT(27,v22[2])
        PUT(19,v32[0]) PUT(20,v32[1]) PUT(21,v32[2])
      }
#undef PUT
    }
    __syncthreads();
    // ---- phase 2: direct table loads, fully static schedule ----
#pragma unroll 4
    for (int j=0; j<CH; ++j){
      if (j < cnt){
        const float* __restrict__ wr0 = tab + (size_t)SiT[half][j]*336;
        const float* __restrict__ wr1 = wr0 + 336;
        const float* __restrict__ IA = SIA[half][j];
        const float* __restrict__ IB = SIB[half][j];
        acc0 = fmaf(wr0[wo[0]], IA[ioS[0]], acc0); acc0 = fmaf(wr1[wo[0]], IB[ioS[0]], acc0);
        acc0 = fmaf(wr0[wo[1]], IA[ioS[1]], acc0); acc0 = fmaf(wr1[wo[1]], IB[ioS[1]], acc0);
        acc0 = fmaf(wr0[wo[2]], IA[ioS[2]], acc0); acc0 = fmaf(wr1[wo[2]], IB[ioS[2]], acc0);
        acc0 = fmaf(wr0[wo[3]], IA[ioS[3]], acc0); acc0 = fmaf(wr1[wo[3]], IB[ioS[3]], acc0);
        acc1 = fmaf(wr0[wo[4]], IA[ioS[4]], acc1); acc1 = fmaf(wr1[wo[4]], IB[ioS[4]], acc1);
        acc1 = fmaf(wr0[wo[5]], IA[ioS[5]], acc1); acc1 = fmaf(wr1[wo[5]], IB[ioS[5]], acc1);
        acc1 = fmaf(wr0[wo[6]], IA[ioS[6]], acc1); acc1 = fmaf(wr1[wo[6]], IB[ioS[6]], acc1);
        acc1 = fmaf(wr0[wo[7]], IA[ioS[7]], acc1); acc1 = fmaf(wr1[wo[7]], IB[ioS[7]], acc1);
      }
    }
  }

  // ---- fused gate epilogue ----
  const float inv = 0.5129891760f;
  if (lane < 16){
    SG[half][2*lane]   = acc0*0.5f*inv;
    SG[half][2*lane+1] = acc1*0.5f*inv;
  }
  __syncthreads();
  float* __restrict__ o = xg + (size_t)node*64;
  if (lane < 16){
    o[lane] = fmaxf(SG[half][lane], 0.0f);                 // se
  } else if (lane < 40){
    int idx = lane-16;
    float vv = (acc0+acc1)*0.4082482905f*inv;
    o[16+idx] = vv * fmaxf(SG[half][gu0], 0.0f);           // v1o (u<8)
  } else if (lane < 52){
    int m = lane-40;
    float vv0 = acc0*0.5773502692f*inv;
    float vv1 = acc1*0.5773502692f*inv;
    o[40+2*m]   = vv0 * fmaxf(SG[half][gu0], 0.0f);        // v1e (u<8)
    o[40+2*m+1] = vv1 * fmaxf(SG[half][gu1], 0.0f);
  }
}

// ---------------- fctp2 per edge -> e2buf[E][4] (pruned) ----------------
__global__ __launch_bounds__(256) void k_tp2(
    const float* __restrict__ pos, const int* __restrict__ src, const int* __restrict__ dst, int E,
    const float* __restrict__ xg, const float* __restrict__ tab,
    float* __restrict__ e2buf, CGPack cg)
{
  const int e = blockIdx.x*256 + threadIdx.x;
  if (e>=E) return;
  const int s = src[e], d = dst[e];
  float ax=pos[3*s]-pos[3*d], ay=pos[3*s+1]-pos[3*d+1], az=pos[3*s+2]-pos[3*d+2];
  float r = sqrtf(ax*ax+ay*ay+az*az);
  float ir = 1.0f/r;
  float x=ax*ir, y=ay*ir, z=az*ir;
  float f = r * 1638.0f;
  int i0 = (int)f; if (i0 > T_TAB-2) i0 = T_TAB-2;
  const float al = f - (float)i0;
  const float* __restrict__ w0 = tab + (size_t)i0*336 + 272;
  const float* __restrict__ w1 = w0 + 336;
  float wse[16], wA[8], wB[8], wC[8];
#pragma unroll
  for (int j=0;j<16;j+=4){
    float4 p = *(const float4*)(w0+j);
    float4 q = *(const float4*)(w1+j);
    wse[j+0]=fmaf(al,q.x-p.x,p.x); wse[j+1]=fmaf(al,q.y-p.y,p.y);
    wse[j+2]=fmaf(al,q.z-p.z,p.z); wse[j+3]=fmaf(al,q.w-p.w,p.w);
  }
#pragma unroll
  for (int j=0;j<8;j+=4){
    float4 p = *(const float4*)(w0+16+j); float4 q = *(const float4*)(w1+16+j);
    wA[j+0]=fmaf(al,q.x-p.x,p.x); wA[j+1]=fmaf(al,q.y-p.y,p.y);
    wA[j+2]=fmaf(al,q.z-p.z,p.z); wA[j+3]=fmaf(al,q.w-p.w,p.w);
    p = *(const float4*)(w0+32+j); q = *(const float4*)(w1+32+j);
    wB[j+0]=fmaf(al,q.x-p.x,p.x); wB[j+1]=fmaf(al,q.y-p.y,p.y);
    wB[j+2]=fmaf(al,q.z-p.z,p.z); wB[j+3]=fmaf(al,q.w-p.w,p.w);
    p = *(const float4*)(w0+48+j); q = *(const float4*)(w1+48+j);
    wC[j+0]=fmaf(al,q.x-p.x,p.x); wC[j+1]=fmaf(al,q.y-p.y,p.y);
    wC[j+2]=fmaf(al,q.z-p.z,p.z); wC[j+3]=fmaf(al,q.w-p.w,p.w);
  }
  const float s3=1.73205081f, s5=2.23606798f, s15=3.87298335f;
  float Y[9];
  Y[0]=1.0f;
  Y[1]=s3*y; Y[2]=s3*z; Y[3]=s3*x;
  Y[4]=s15*x*y; Y[5]=s15*y*z; Y[6]=0.5f*s5*(3.0f*z*z-1.0f); Y[7]=s15*x*z; Y[8]=0.5f*s15*(x*x-y*y);
  const float* __restrict__ g = xg + (size_t)s*64;
  float se[16], vo[24], ve[24];
#pragma unroll
  for (int jj=0;jj<4;++jj){ float4 t=((const float4*)g)[jj];
    se[4*jj]=t.x; se[4*jj+1]=t.y; se[4*jj+2]=t.z; se[4*jj+3]=t.w; }
#pragma unroll
  for (int jj=0;jj<6;++jj){ float4 t=((const float4*)(g+16))[jj];
    vo[4*jj]=t.x; vo[4*jj+1]=t.y; vo[4*jj+2]=t.z; vo[4*jj+3]=t.w; }
#pragma unroll
  for (int jj=0;jj<6;++jj){ float4 t=((const float4*)(g+40))[jj];
    ve[4*jj]=t.x; ve[4*jj+1]=t.y; ve[4*jj+2]=t.z; ve[4*jj+3]=t.w; }

  float SA=0.0f;
#pragma unroll
  for (int u=0;u<16;++u) SA = fmaf(wse[u], se[u], SA);
  float AB[3]={0,0,0}, AC[3]={0,0,0}, AD[3]={0,0,0};
#pragma unroll
  for (int u=0;u<8;++u)
#pragma unroll
    for (int i=0;i<3;++i){
      AB[i]=fmaf(wA[u], vo[u*3+i], AB[i]);
      AC[i]=fmaf(wB[u], vo[u*3+i], AC[i]);
      AD[i]=fmaf(wC[u], ve[u*3+i], AD[i]);
    }
  float e2[3]={0,0,0};
#pragma unroll
  for (int j=0;j<3;++j){ float t=SA*Y[1+j];
#pragma unroll
    for (int k=0;k<3;++k) e2[k]=fmaf(t, cg.c011[j*3+k], e2[k]); }
#pragma unroll
  for (int i=0;i<3;++i){ float t=AB[i]*Y[0];
#pragma unroll
    for (int k=0;k<3;++k) e2[k]=fmaf(t, cg.c101[i*3+k], e2[k]); }
#pragma unroll
  for (int i=0;i<3;++i)
#pragma unroll
    for (int j=0;j<5;++j){ float t=AC[i]*Y[4+j];
#pragma unroll
      for (int k=0;k<3;++k) e2[k]=fmaf(t, cg.c121[(i*5+j)*3+k], e2[k]); }
#pragma unroll
  for (int i=0;i<3;++i)
#pragma unroll
    for (int j=0;j<3;++j){ float t=AD[i]*Y[1+j];
#pragma unroll
      for (int k=0;k<3;++k) e2[k]=fmaf(t, cg.c111[(i*3+j)*3+k], e2[k]); }

  *(float4*)(e2buf + (size_t)e*4) = make_float4(e2[0], e2[1], e2[2], 0.0f);
}

// ---------------- final gather ----------------
__global__ __launch_bounds__(256) void k_out(
    const float* __restrict__ e2buf, const int* __restrict__ rowptr,
    float* __restrict__ out)
{
  const int t = blockIdx.x*256 + threadIdx.x;
  const int n = t>>2, k = t&3;
  if (n>=NN) return;
  const int r0=rowptr[n], r1=rowptr[n+1];
  float a=0.f;
  for (int e=r0;e<r1;++e) a += e2buf[(size_t)e*4 + k];
  const float sc = 0.0641236437f;  // (1/sqrt(64)) * 1/sqrt(3.8)
  if (k<3) out[(size_t)n*3 + k] = a*sc;
}

// ---------------- host launcher ----------------
extern "C" void kernel_launch(void* const* d_in, const int* in_sizes, int n_in,
                              void* d_out, int out_size, void* d_ws, size_t ws_size,
                              hipStream_t stream)
{
  (void)n_in; (void)ws_size; (void)out_size;
  const float* pos = (const float*)d_in[0];
  const int*   src = (const int*)d_in[1];
  const int*   dst = (const int*)d_in[2];
  const float* W1  = (const float*)d_in[3];
  const float* W2  = (const float*)d_in[4];
  const float* W1f = (const float*)d_in[5];
  const float* W2f = (const float*)d_in[6];
  const int E = in_sizes[1];

  char* ws = (char*)d_ws;
  float* xacc  = (float*)ws;                     // NN*16
  float* xg    = xacc + (size_t)NN*16;           // NN*64
  float* tab   = xg + (size_t)NN*64;             // T_TAB*336
  float* e2buf = tab + (size_t)T_TAB*336;        // E*4
  int*   rowptr= (int*)(e2buf + (size_t)E*4);    // NN+1

  CGPack cg;
  build_cg(cg);

  k_table<<<T_TAB/G_TAB, 256, 0, stream>>>(W1, W2, W1f, W2f, tab);
  k_rowptr<<<(NN+1+255)/256, 256, 0, stream>>>(dst, E, rowptr);
  k_x<<<(NN*4)/256, 256, 0, stream>>>(pos, src, rowptr, xacc);
  k_tp1<<<NN/2, 128, 0, stream>>>(pos, src, rowptr, xacc, tab, xg, cg);
  k_tp2<<<(E + 255) / 256, 256, 0, stream>>>(pos, src, dst, E, xg, tab, e2buf, cg);
  k_out<<<(NN*4)/256, 256, 0, stream>>>(e2buf, rowptr, (float*)d_out);
}

// Round 5
// 231.482 us; speedup vs baseline: 2.1054x; 1.0783x over previous
//
#include <hip/hip_runtime.h>
#include <cmath>
#include <complex>

#define T_TAB 4096
#define G_TAB 8
#define NN 16384
#define CH 16

// ---------------- CG tables (exact host-side port of the reference) ----------------
struct CGPack {
  float c000[1];
  float c110[9];
  float c220[25];
  float c330[49];
  float c011[9];
  float c101[9];
  float c111[27];
  float c121[45];
  float c211[45];
  float c221[75];
  float c231[105];
  float c321[105];
  float c331[147];
};

static double factd(int n){ double r=1.0; for(int i=2;i<=n;++i) r*=(double)i; return r; }

static double cg_coef(int j1,int m1,int j2,int m2,int j3,int m3){
  double pref = sqrt((2.0*j3+1.0)*factd(j3+j1-j2)*factd(j3-j1+j2)*factd(j1+j2-j3)/factd(j1+j2+j3+1));
  pref *= sqrt(factd(j3+m3)*factd(j3-m3)*factd(j1-m1)*factd(j1+m1)*factd(j2-m2)*factd(j2+m2));
  double s=0.0;
  for(int k=0;k<=j1+j2-j3;++k){
    int a0=k,a1=j1+j2-j3-k,a2=j1-m1-k,a3=j2+m2-k,a4=j3-j2+m1+k,a5=j3-j1-m2+k;
    if(a0<0||a1<0||a2<0||a3<0||a4<0||a5<0) continue;
    double d=factd(a0)*factd(a1)*factd(a2)*factd(a3)*factd(a4)*factd(a5);
    s += ((k&1)?-1.0:1.0)/d;
  }
  return pref*s;
}

static void u_fill(int l, std::complex<double> U[7][7]){
  for(int i=0;i<7;++i) for(int j=0;j<7;++j) U[i][j]=std::complex<double>(0.0,0.0);
  const double is2 = 1.0/sqrt(2.0);
  U[l][l]=1.0;
  for(int m=1;m<=l;++m){
    double sgn = (m&1)?-1.0:1.0;
    U[l+m][l+m] = sgn*is2;
    U[l+m][l-m] = is2;
    U[l-m][l-m] = std::complex<double>(0.0, is2);
    U[l-m][l+m] = std::complex<double>(0.0, -sgn*is2);
  }
}

static void cg_fill(int l1,int l2,int l3, float* out){
  int n1=2*l1+1,n2=2*l2+1,n3=2*l3+1;
  double Cc[7][7][7];
  for(int a=0;a<7;++a)for(int b=0;b<7;++b)for(int c=0;c<7;++c) Cc[a][b][c]=0.0;
  for(int m1=-l1;m1<=l1;++m1)
    for(int m2=-l2;m2<=l2;++m2){
      int m3=m1+m2;
      if(m3>=-l3&&m3<=l3) Cc[m1+l1][m2+l2][m3+l3]=cg_coef(l1,m1,l2,m2,l3,m3);
    }
  std::complex<double> U1[7][7],U2[7][7],U3[7][7];
  u_fill(l1,U1); u_fill(l2,U2); u_fill(l3,U3);
  std::complex<double> Cr[343];
  double sre=0.0,sim=0.0;
  for(int a=0;a<n1;++a)for(int b=0;b<n2;++b)for(int c=0;c<n3;++c){
    std::complex<double> acc(0.0,0.0);
    for(int u=0;u<n1;++u)for(int v=0;v<n2;++v)for(int w=0;w<n3;++w){
      double cc=Cc[u][v][w];
      if(cc==0.0) continue;
      acc += U1[a][u]*U2[b][v]*std::conj(U3[c][w])*cc;
    }
    Cr[(a*n2+b)*n3+c]=acc;
    sre+=fabs(acc.real()); sim+=fabs(acc.imag());
  }
  bool useim = sim>sre;
  for(int idx=0;idx<n1*n2*n3;++idx) out[idx]=(float)(useim?Cr[idx].imag():Cr[idx].real());
}

static void build_cg(CGPack& P){
  cg_fill(0,0,0,P.c000);
  cg_fill(1,1,0,P.c110);
  cg_fill(2,2,0,P.c220);
  cg_fill(3,3,0,P.c330);
  cg_fill(0,1,1,P.c011);
  cg_fill(1,0,1,P.c101);
  cg_fill(1,1,1,P.c111);
  cg_fill(1,2,1,P.c121);
  cg_fill(2,1,1,P.c211);
  cg_fill(2,2,1,P.c221);
  cg_fill(2,3,1,P.c231);
  cg_fill(3,2,1,P.c321);
  cg_fill(3,3,1,P.c331);
}

// ---------------- device helpers ----------------
__device__ __forceinline__ float soh(float r, float c){
  float d = (r - c) * 2.0f;
  float d2 = d*d;
  return (d2 < 1.0f) ? 1.14136f * expf(2.0f + 1.0f/(d2-1.0f)) : 0.0f;
}

// ---------------- radial MLP lookup table: tab[T_TAB][336] ----------------
__global__ __launch_bounds__(256) void k_table(
    const float* __restrict__ W1, const float* __restrict__ W2,
    const float* __restrict__ W1f, const float* __restrict__ W2f,
    float* __restrict__ tab)
{
  __shared__ float h[G_TAB][256];
  __shared__ float hf[G_TAB][256];
  const int c = threadIdx.x;
  const int t0 = blockIdx.x * G_TAB;
  const float dr = 2.5f / (float)(T_TAB-1);
  const float w1a = W1[c], w1b = W1[256+c], w1c = W1[512+c];
  const float f1a = W1f[c], f1b = W1f[256+c], f1c = W1f[512+c];
#pragma unroll
  for (int g=0; g<G_TAB; ++g){
    float r = (float)(t0+g) * dr;
    float e0 = soh(r,1.0f), e1 = soh(r,1.5f), e2 = soh(r,2.0f);
    h[g][c]  = fmaxf(e0*w1a + e1*w1b + e2*w1c, 0.0f);
    hf[g][c] = fmaxf(e0*f1a + e1*f1b + e2*f1c, 0.0f);
  }
  __syncthreads();
  for (int j = c; j < 336; j += 256){
    float acc[G_TAB];
#pragma unroll
    for (int g=0; g<G_TAB; ++g) acc[g]=0.0f;
    if (j < 272){
      for (int cc=0; cc<256; ++cc){
        float wv = W2[cc*272 + j];
#pragma unroll
        for (int g=0; g<G_TAB; ++g) acc[g] = fmaf(h[g][cc], wv, acc[g]);
      }
    } else {
      int jj = j - 272;
      for (int cc=0; cc<256; ++cc){
        float wv = W2f[cc*64 + jj];
#pragma unroll
        for (int g=0; g<G_TAB; ++g) acc[g] = fmaf(hf[g][cc], wv, acc[g]);
      }
    }
#pragma unroll
    for (int g=0; g<G_TAB; ++g) tab[(size_t)(t0+g)*336 + j] = acc[g] * 0.0625f;
  }
}

// ---------------- rowptr: dst is globally non-decreasing -> CSR via binary search ----
__global__ __launch_bounds__(256) void k_rowptr(
    const int* __restrict__ dst, int E, int* __restrict__ rowptr)
{
  const int n = blockIdx.x*256 + threadIdx.x;
  if (n > NN) return;
  int lo=0, hi=E;
  while (lo < hi){ int mid=(lo+hi)>>1; if (dst[mid] < n) lo=mid+1; else hi=mid; }
  rowptr[n]=lo;
}

// ---------------- x = segsum(sph_harm): 4 lanes/node, each edge touched once -------
__global__ __launch_bounds__(256) void k_x(
    const float* __restrict__ pos, const int* __restrict__ src,
    const int* __restrict__ rowptr, float* __restrict__ xacc)
{
  const int t = blockIdx.x*256 + threadIdx.x;
  const int n = t>>2, q = t&3;
  if (n>=NN) return;
  const int r0=rowptr[n], r1=rowptr[n+1];
  const float pdx=pos[3*n], pdy=pos[3*n+1], pdz=pos[3*n+2];
  const float s3=1.73205081f, s5=2.23606798f, s15=3.87298335f;
  const float c33=2.09165007f, c32=10.2469508f, c31=1.62018517f, c30=1.32287566f, cp2=5.12347538f;
  float a0=0,a1=0,a2=0,a3=0,a4=0,a5=0,a6=0,a7=0,a8=0,a9=0,a10=0,a11=0,a12=0,a13=0,a14=0,a15=0;
  for (int e=r0+q; e<r1; e+=4){
    const int s=src[e];
    float ax=pos[3*s]-pdx, ay=pos[3*s+1]-pdy, az=pos[3*s+2]-pdz;
    float ir = 1.0f/sqrtf(ax*ax+ay*ay+az*az);
    float x=ax*ir, y=ay*ir, z=az*ir;
    a0+=1.0f; a1+=s3*y; a2+=s3*z; a3+=s3*x;
    a4+=s15*x*y; a5+=s15*y*z; a6+=0.5f*s5*(3.0f*z*z-1.0f); a7+=s15*x*z;
    a8+=0.5f*s15*(x*x-y*y); a9+=c33*y*(3.0f*x*x-y*y); a10+=c32*x*y*z; a11+=c31*y*(5.0f*z*z-1.0f);
    a12+=c30*(5.0f*z*z*z-3.0f*z); a13+=c31*x*(5.0f*z*z-1.0f); a14+=cp2*z*(x*x-y*y);
    a15+=c33*x*(x*x-3.0f*y*y);
  }
#define RED(v) v += __shfl_xor(v,1); v += __shfl_xor(v,2);
  RED(a0) RED(a1) RED(a2) RED(a3) RED(a4) RED(a5) RED(a6) RED(a7)
  RED(a8) RED(a9) RED(a10) RED(a11) RED(a12) RED(a13) RED(a14) RED(a15)
#undef RED
  float o0,o1,o2,o3;
  if (q==0){ o0=a0; o1=a1; o2=a2; o3=a3; }
  else if (q==1){ o0=a4; o1=a5; o2=a6; o3=a7; }
  else if (q==2){ o0=a8; o1=a9; o2=a10; o3=a11; }
  else { o0=a12; o1=a13; o2=a14; o3=a15; }
  *(float4*)(xacc + (size_t)n*16 + q*4) = make_float4(o0,o1,o2,o3);
}

// ---------------- fctp1 + gate fused: ONE WAVE PER NODE ----------------
// Phase 1: 4 lanes/edge -> 31 CG intermediates, stored as I*(1-al), I*al in LDS
//          (rows padded to 33 floats: bank = (je+slot)%32, conflict-free).
// Phase 2: uniform 8x(weight,slot) register schedule, 2 accs/lane, direct tab loads.
// Epilogue: gate via 32-float LDS exchange; writes compact xg[NN][64].
__global__ __launch_bounds__(64) void k_tp1(
    const float* __restrict__ pos, const int* __restrict__ src,
    const int* __restrict__ rowptr, const float* __restrict__ xacc,
    const float* __restrict__ tab, float* __restrict__ xg, CGPack cg)
{
  const int lane = threadIdx.x;
  const int node = blockIdx.x;
  __shared__ float SIA[CH][33];
  __shared__ float SIB[CH][33];
  __shared__ int   SiT[CH];
  __shared__ float SG[32];
  const int r0 = rowptr[node], r1 = rowptr[node+1];
  const int nch = (r1 - r0 + CH - 1) / CH;

  // ---- uniform per-lane schedule: 8 (weight-offset, LDS-slot) pairs, 2 accs ----
  int wo[8], ioS[8];
#pragma unroll
  for (int p=0;p<8;++p){ wo[p]=0; ioS[p]=31; }   // dummies: weight 0 x zero-slot
  int gu0=16, gu1=16;                            // gate indices into SG
  if (lane < 16){
#pragma unroll
    for (int s=0;s<2;++s){
      int a = 2*lane+s;
      int b0,b1,b2,b3;
      if (a<16){ b0=a; b1=64+a; b2=144+a; b3=224+a; }
      else if (a<24){ int u=a-16; b0=16+u; b1=80+u; b2=160+u; b3=240+u; }
      else { int u=a-24; b0=24+u; b1=88+u; b2=168+u; b3=248+u; }
      wo[4*s+0]=b0; ioS[4*s+0]=0;
      wo[4*s+1]=b1; ioS[4*s+1]=1;
      wo[4*s+2]=b2; ioS[4*s+2]=2;
      wo[4*s+3]=b3; ioS[4*s+3]=3;
    }
  } else if (lane < 40){
    int idx=lane-16, u=idx/3, k=idx-3*u;
    wo[0]=32+u;  ioS[0]=4+k;    // v01
    wo[1]=48+u;  ioS[1]=7+k;    // v10
    wo[2]=112+u; ioS[2]=10+k;   // v12
    wo[3]=128+u; ioS[3]=13+k;   // v21
    wo[4]=192+u; ioS[4]=16+k;   // v23
    wo[5]=208+u; ioS[5]=19+k;   // v32
    gu0 = 16+u;
  } else if (lane < 52){
    int m=lane-40;
    int c0=2*m,   u0=c0/3, k0=c0-3*u0;
    int c1=2*m+1, u1=c1/3, k1=c1-3*u1;
    wo[0]=96+u0;  ioS[0]=22+k0;  // v11
    wo[1]=176+u0; ioS[1]=25+k0;  // v22
    wo[2]=256+u0; ioS[2]=28+k0;  // v33
    wo[4]=96+u1;  ioS[4]=22+k1;
    wo[5]=176+u1; ioS[5]=25+k1;
    wo[6]=256+u1; ioS[6]=28+k1;
    gu0 = 24+u0; gu1 = 24+u1;
  }

  const float pdx=pos[3*node], pdy=pos[3*node+1], pdz=pos[3*node+2];
  const int je = lane & 15, part = lane >> 4;
  float acc0 = 0.f, acc1 = 0.f;

  for (int t=0; t<nch; ++t){
    const int e0 = r0 + t*CH;
    const int cnt = min(CH, r1-e0);
    __syncthreads();
    if (je < cnt){
      const int e = e0 + je;
      const int s = src[e];
      float ax=pos[3*s]-pdx, ay=pos[3*s+1]-pdy, az=pos[3*s+2]-pdz;
      float r = sqrtf(ax*ax+ay*ay+az*az);
      float ir = 1.0f/r;
      float x=ax*ir, y=ay*ir, z=az*ir;
      float f = r * 1638.0f;                    // (T_TAB-1)/2.5
      int i0 = (int)f; if (i0 > T_TAB-2) i0 = T_TAB-2;
      float bl = f - (float)i0;
      float aw = 1.0f - bl;

      const float s3=1.73205081f, s5=2.23606798f, s15=3.87298335f;
      const float c33=2.09165007f, c32=10.2469508f, c31=1.62018517f, c30=1.32287566f, cp2=5.12347538f;
      float Y[16];
      Y[0]=1.0f;
      Y[1]=s3*y; Y[2]=s3*z; Y[3]=s3*x;
      Y[4]=s15*x*y; Y[5]=s15*y*z; Y[6]=0.5f*s5*(3.0f*z*z-1.0f); Y[7]=s15*x*z; Y[8]=0.5f*s15*(x*x-y*y);
      Y[9]=c33*y*(3.0f*x*x-y*y); Y[10]=c32*x*y*z; Y[11]=c31*y*(5.0f*z*z-1.0f);
      Y[12]=c30*(5.0f*z*z*z-3.0f*z); Y[13]=c31*x*(5.0f*z*z-1.0f); Y[14]=cp2*z*(x*x-y*y);
      Y[15]=c33*x*(x*x-3.0f*y*y);
      float X[16];
      {
        const float inv = 0.5129891760f;           // 1/sqrt(3.8)
        const float4* q4 = (const float4*)(xacc + (size_t)s*16);
        float4 a=q4[0],b=q4[1],cc4=q4[2],d4=q4[3];
        X[0]=a.x*inv;X[1]=a.y*inv;X[2]=a.z*inv;X[3]=a.w*inv;
        X[4]=b.x*inv;X[5]=b.y*inv;X[6]=b.z*inv;X[7]=b.w*inv;
        X[8]=cc4.x*inv;X[9]=cc4.y*inv;X[10]=cc4.z*inv;X[11]=cc4.w*inv;
        X[12]=d4.x*inv;X[13]=d4.y*inv;X[14]=d4.z*inv;X[15]=d4.w*inv;
      }
      float* A_ = SIA[je];
      float* B_ = SIB[je];
#define PUT(slot, val) { float vv_=(val); A_[slot]=vv_*aw; B_[slot]=vv_*bl; }
      if (part == 0){
        float t0v = cg.c000[0]*X[0]*Y[0];
        float t1v=0.f, t2v=0.f, t3v=0.f;
#pragma unroll
        for (int i=0;i<3;++i)
#pragma unroll
          for (int j=0;j<3;++j) t1v = fmaf(X[1+i]*Y[1+j], cg.c110[i*3+j], t1v);
#pragma unroll
        for (int i=0;i<5;++i)
#pragma unroll
          for (int j=0;j<5;++j) t2v = fmaf(X[4+i]*Y[4+j], cg.c220[i*5+j], t2v);
#pragma unroll
        for (int i=0;i<7;++i)
#pragma unroll
          for (int j=0;j<7;++j) t3v = fmaf(X[9+i]*Y[9+j], cg.c330[i*7+j], t3v);
        float v12[3]={0,0,0};
#pragma unroll
        for (int i=0;i<3;++i)
#pragma unroll
          for (int j=0;j<5;++j){ float tt=X[1+i]*Y[4+j];
#pragma unroll
            for (int k=0;k<3;++k) v12[k]=fmaf(tt, cg.c121[(i*5+j)*3+k], v12[k]); }
        PUT(0,t0v) PUT(1,t1v) PUT(2,t2v) PUT(3,t3v)
        PUT(10,v12[0]) PUT(11,v12[1]) PUT(12,v12[2])
        A_[31]=0.0f; B_[31]=0.0f;
        SiT[je]=i0;
      } else if (part == 1){
        float v01[3]={0,0,0}, v10[3]={0,0,0}, v33[3]={0,0,0};
#pragma unroll
        for (int j=0;j<3;++j){ float tt=X[0]*Y[1+j];
#pragma unroll
          for (int k=0;k<3;++k) v01[k]=fmaf(tt, cg.c011[j*3+k], v01[k]); }
#pragma unroll
        for (int i=0;i<3;++i){ float tt=X[1+i]*Y[0];
#pragma unroll
          for (int k=0;k<3;++k) v10[k]=fmaf(tt, cg.c101[i*3+k], v10[k]); }
#pragma unroll
        for (int i=0;i<7;++i)
#pragma unroll
          for (int j=0;j<7;++j){ float tt=X[9+i]*Y[9+j];
#pragma unroll
            for (int k=0;k<3;++k) v33[k]=fmaf(tt, cg.c331[(i*7+j)*3+k], v33[k]); }
        PUT(4,v01[0]) PUT(5,v01[1]) PUT(6,v01[2])
        PUT(7,v10[0]) PUT(8,v10[1]) PUT(9,v10[2])
        PUT(28,v33[0]) PUT(29,v33[1]) PUT(30,v33[2])
      } else if (part == 2){
        float v11[3]={0,0,0}, v21[3]={0,0,0}, v23[3]={0,0,0};
#pragma unroll
        for (int i=0;i<3;++i)
#pragma unroll
          for (int j=0;j<3;++j){ float tt=X[1+i]*Y[1+j];
#pragma unroll
            for (int k=0;k<3;++k) v11[k]=fmaf(tt, cg.c111[(i*3+j)*3+k], v11[k]); }
#pragma unroll
        for (int i=0;i<5;++i)
#pragma unroll
          for (int j=0;j<3;++j){ float tt=X[4+i]*Y[1+j];
#pragma unroll
            for (int k=0;k<3;++k) v21[k]=fmaf(tt, cg.c211[(i*3+j)*3+k], v21[k]); }
#pragma unroll
        for (int i=0;i<5;++i)
#pragma unroll
          for (int j=0;j<7;++j){ float tt=X[4+i]*Y[9+j];
#pragma unroll
            for (int k=0;k<3;++k) v23[k]=fmaf(tt, cg.c231[(i*7+j)*3+k], v23[k]); }
        PUT(22,v11[0]) PUT(23,v11[1]) PUT(24,v11[2])
        PUT(13,v21[0]) PUT(14,v21[1]) PUT(15,v21[2])
        PUT(16,v23[0]) PUT(17,v23[1]) PUT(18,v23[2])
      } else {
        float v22[3]={0,0,0}, v32[3]={0,0,0};
#pragma unroll
        for (int i=0;i<5;++i)
#pragma unroll
          for (int j=0;j<5;++j){ float tt=X[4+i]*Y[4+j];
#pragma unroll
            for (int k=0;k<3;++k) v22[k]=fmaf(tt, cg.c221[(i*5+j)*3+k], v22[k]); }
#pragma unroll
        for (int i=0;i<7;++i)
#pragma unroll
          for (int j=0;j<5;++j){ float tt=X[9+i]*Y[4+j];
#pragma unroll
            for (int k=0;k<3;++k) v32[k]=fmaf(tt, cg.c321[(i*5+j)*3+k], v32[k]); }
        PUT(25,v22[0]) PUT(26,v22[1]) PUT(27,v22[2])
        PUT(19,v32[0]) PUT(20,v32[1]) PUT(21,v32[2])
      }
#undef PUT
    }
    __syncthreads();
    // ---- phase 2: direct table loads, fully static schedule ----
#pragma unroll 4
    for (int j=0; j<CH; ++j){
      if (j < cnt){
        const float* __restrict__ wr0 = tab + (size_t)SiT[j]*336;
        const float* __restrict__ wr1 = wr0 + 336;
        const float* __restrict__ IA = SIA[j];
        const float* __restrict__ IB = SIB[j];
        acc0 = fmaf(wr0[wo[0]], IA[ioS[0]], acc0); acc0 = fmaf(wr1[wo[0]], IB[ioS[0]], acc0);
        acc0 = fmaf(wr0[wo[1]], IA[ioS[1]], acc0); acc0 = fmaf(wr1[wo[1]], IB[ioS[1]], acc0);
        acc0 = fmaf(wr0[wo[2]], IA[ioS[2]], acc0); acc0 = fmaf(wr1[wo[2]], IB[ioS[2]], acc0);
        acc0 = fmaf(wr0[wo[3]], IA[ioS[3]], acc0); acc0 = fmaf(wr1[wo[3]], IB[ioS[3]], acc0);
        acc1 = fmaf(wr0[wo[4]], IA[ioS[4]], acc1); acc1 = fmaf(wr1[wo[4]], IB[ioS[4]], acc1);
        acc1 = fmaf(wr0[wo[5]], IA[ioS[5]], acc1); acc1 = fmaf(wr1[wo[5]], IB[ioS[5]], acc1);
        acc1 = fmaf(wr0[wo[6]], IA[ioS[6]], acc1); acc1 = fmaf(wr1[wo[6]], IB[ioS[6]], acc1);
        acc1 = fmaf(wr0[wo[7]], IA[ioS[7]], acc1); acc1 = fmaf(wr1[wo[7]], IB[ioS[7]], acc1);
      }
    }
  }

  // ---- fused gate epilogue ----
  const float inv = 0.5129891760f;
  if (lane < 16){
    SG[2*lane]   = acc0*0.5f*inv;
    SG[2*lane+1] = acc1*0.5f*inv;
  }
  __syncthreads();
  float* __restrict__ o = xg + (size_t)node*64;
  if (lane < 16){
    o[lane] = fmaxf(SG[lane], 0.0f);                       // se
  } else if (lane < 40){
    int idx = lane-16;
    float vv = (acc0+acc1)*0.4082482905f*inv;
    o[16+idx] = vv * fmaxf(SG[gu0], 0.0f);                 // v1o (u<8)
  } else if (lane < 52){
    int m = lane-40;
    float vv0 = acc0*0.5773502692f*inv;
    float vv1 = acc1*0.5773502692f*inv;
    o[40+2*m]   = vv0 * fmaxf(SG[gu0], 0.0f);              // v1e (u<8)
    o[40+2*m+1] = vv1 * fmaxf(SG[gu1], 0.0f);
  }
}

// ---------------- fctp2 per edge -> e2buf[E][4] (pruned) ----------------
__global__ __launch_bounds__(256) void k_tp2(
    const float* __restrict__ pos, const int* __restrict__ src, const int* __restrict__ dst, int E,
    const float* __restrict__ xg, const float* __restrict__ tab,
    float* __restrict__ e2buf, CGPack cg)
{
  const int e = blockIdx.x*256 + threadIdx.x;
  if (e>=E) return;
  const int s = src[e], d = dst[e];
  float ax=pos[3*s]-pos[3*d], ay=pos[3*s+1]-pos[3*d+1], az=pos[3*s+2]-pos[3*d+2];
  float r = sqrtf(ax*ax+ay*ay+az*az);
  float ir = 1.0f/r;
  float x=ax*ir, y=ay*ir, z=az*ir;
  float f = r * 1638.0f;
  int i0 = (int)f; if (i0 > T_TAB-2) i0 = T_TAB-2;
  const float al = f - (float)i0;
  const float* __restrict__ w0 = tab + (size_t)i0*336 + 272;
  const float* __restrict__ w1 = w0 + 336;
  float wse[16], wA[8], wB[8], wC[8];
#pragma unroll
  for (int j=0;j<16;j+=4){
    float4 p = *(const float4*)(w0+j);
    float4 q = *(const float4*)(w1+j);
    wse[j+0]=fmaf(al,q.x-p.x,p.x); wse[j+1]=fmaf(al,q.y-p.y,p.y);
    wse[j+2]=fmaf(al,q.z-p.z,p.z); wse[j+3]=fmaf(al,q.w-p.w,p.w);
  }
#pragma unroll
  for (int j=0;j<8;j+=4){
    float4 p = *(const float4*)(w0+16+j); float4 q = *(const float4*)(w1+16+j);
    wA[j+0]=fmaf(al,q.x-p.x,p.x); wA[j+1]=fmaf(al,q.y-p.y,p.y);
    wA[j+2]=fmaf(al,q.z-p.z,p.z); wA[j+3]=fmaf(al,q.w-p.w,p.w);
    p = *(const float4*)(w0+32+j); q = *(const float4*)(w1+32+j);
    wB[j+0]=fmaf(al,q.x-p.x,p.x); wB[j+1]=fmaf(al,q.y-p.y,p.y);
    wB[j+2]=fmaf(al,q.z-p.z,p.z); wB[j+3]=fmaf(al,q.w-p.w,p.w);
    p = *(const float4*)(w0+48+j); q = *(const float4*)(w1+48+j);
    wC[j+0]=fmaf(al,q.x-p.x,p.x); wC[j+1]=fmaf(al,q.y-p.y,p.y);
    wC[j+2]=fmaf(al,q.z-p.z,p.z); wC[j+3]=fmaf(al,q.w-p.w,p.w);
  }
  const float s3=1.73205081f, s5=2.23606798f, s15=3.87298335f;
  float Y[9];
  Y[0]=1.0f;
  Y[1]=s3*y; Y[2]=s3*z; Y[3]=s3*x;
  Y[4]=s15*x*y; Y[5]=s15*y*z; Y[6]=0.5f*s5*(3.0f*z*z-1.0f); Y[7]=s15*x*z; Y[8]=0.5f*s15*(x*x-y*y);
  const float* __restrict__ g = xg + (size_t)s*64;
  float se[16], vo[24], ve[24];
#pragma unroll
  for (int jj=0;jj<4;++jj){ float4 t=((const float4*)g)[jj];
    se[4*jj]=t.x; se[4*jj+1]=t.y; se[4*jj+2]=t.z; se[4*jj+3]=t.w; }
#pragma unroll
  for (int jj=0;jj<6;++jj){ float4 t=((const float4*)(g+16))[jj];
    vo[4*jj]=t.x; vo[4*jj+1]=t.y; vo[4*jj+2]=t.z; vo[4*jj+3]=t.w; }
#pragma unroll
  for (int jj=0;jj<6;++jj){ float4 t=((const float4*)(g+40))[jj];
    ve[4*jj]=t.x; ve[4*jj+1]=t.y; ve[4*jj+2]=t.z; ve[4*jj+3]=t.w; }

  float SA=0.0f;
#pragma unroll
  for (int u=0;u<16;++u) SA = fmaf(wse[u], se[u], SA);
  float AB[3]={0,0,0}, AC[3]={0,0,0}, AD[3]={0,0,0};
#pragma unroll
  for (int u=0;u<8;++u)
#pragma unroll
    for (int i=0;i<3;++i){
      AB[i]=fmaf(wA[u], vo[u*3+i], AB[i]);
      AC[i]=fmaf(wB[u], vo[u*3+i], AC[i]);
      AD[i]=fmaf(wC[u], ve[u*3+i], AD[i]);
    }
  float e2[3]={0,0,0};
#pragma unroll
  for (int j=0;j<3;++j){ float t=SA*Y[1+j];
#pragma unroll
    for (int k=0;k<3;++k) e2[k]=fmaf(t, cg.c011[j*3+k], e2[k]); }
#pragma unroll
  for (int i=0;i<3;++i){ float t=AB[i]*Y[0];
#pragma unroll
    for (int k=0;k<3;++k) e2[k]=fmaf(t, cg.c101[i*3+k], e2[k]); }
#pragma unroll
  for (int i=0;i<3;++i)
#pragma unroll
    for (int j=0;j<5;++j){ float t=AC[i]*Y[4+j];
#pragma unroll
      for (int k=0;k<3;++k) e2[k]=fmaf(t, cg.c121[(i*5+j)*3+k], e2[k]); }
#pragma unroll
  for (int i=0;i<3;++i)
#pragma unroll
    for (int j=0;j<3;++j){ float t=AD[i]*Y[1+j];
#pragma unroll
      for (int k=0;k<3;++k) e2[k]=fmaf(t, cg.c111[(i*3+j)*3+k], e2[k]); }

  *(float4*)(e2buf + (size_t)e*4) = make_float4(e2[0], e2[1], e2[2], 0.0f);
}

// ---------------- final gather ----------------
__global__ __launch_bounds__(256) void k_out(
    const float* __restrict__ e2buf, const int* __restrict__ rowptr,
    float* __restrict__ out)
{
  const int t = blockIdx.x*256 + threadIdx.x;
  const int n = t>>2, k = t&3;
  if (n>=NN) return;
  const int r0=rowptr[n], r1=rowptr[n+1];
  float a=0.f;
  for (int e=r0;e<r1;++e) a += e2buf[(size_t)e*4 + k];
  const float sc = 0.0641236437f;  // (1/sqrt(64)) * 1/sqrt(3.8)
  if (k<3) out[(size_t)n*3 + k] = a*sc;
}

// ---------------- host launcher ----------------
extern "C" void kernel_launch(void* const* d_in, const int* in_sizes, int n_in,
                              void* d_out, int out_size, void* d_ws, size_t ws_size,
                              hipStream_t stream)
{
  (void)n_in; (void)ws_size; (void)out_size;
  const float* pos = (const float*)d_in[0];
  const int*   src = (const int*)d_in[1];
  const int*   dst = (const int*)d_in[2];
  const float* W1  = (const float*)d_in[3];
  const float* W2  = (const float*)d_in[4];
  const float* W1f = (const float*)d_in[5];
  const float* W2f = (const float*)d_in[6];
  const int E = in_sizes[1];

  char* ws = (char*)d_ws;
  float* xacc  = (float*)ws;                     // NN*16
  float* xg    = xacc + (size_t)NN*16;           // NN*64
  float* tab   = xg + (size_t)NN*64;             // T_TAB*336
  float* e2buf = tab + (size_t)T_TAB*336;        // E*4
  int*   rowptr= (int*)(e2buf + (size_t)E*4);    // NN+1

  CGPack cg;
  build_cg(cg);

  k_table<<<T_TAB/G_TAB, 256, 0, stream>>>(W1, W2, W1f, W2f, tab);
  k_rowptr<<<(NN+1+255)/256, 256, 0, stream>>>(dst, E, rowptr);
  k_x<<<(NN*4)/256, 256, 0, stream>>>(pos, src, rowptr, xacc);
  k_tp1<<<NN, 64, 0, stream>>>(pos, src, rowptr, xacc, tab, xg, cg);
  k_tp2<<<(E + 255) / 256, 256, 0, stream>>>(pos, src, dst, E, xg, tab, e2buf, cg);
  k_out<<<(NN*4)/256, 256, 0, stream>>>(e2buf, rowptr, (float*)d_out);
}